// Round 4
// baseline (856.646 us; speedup 1.0000x reference)
//
#include <hip/hip_runtime.h>
#include <hip/hip_bf16.h>
#include <cstdint>
#include <cstddef>

// Problem constants
static constexpr int N_TOK = 49152;     // B*M = 8192*6
// d_out offsets (floats), outputs concatenated in reference return order
static constexpr size_t OFF_TRAJ     = 0;          // [N,120]
static constexpr size_t OFF_SCORE    = 5898240;    // [N]
static constexpr size_t OFF_LOGITS   = 5947392;    // [N,5]
static constexpr size_t OFF_IDX      = 6193152;    // [N,2]  (ints stored as floats)
static constexpr size_t OFF_AUX      = 6291456;    // [1]
static constexpr size_t OFF_TRAJALL  = 6291457;    // [5,N,120]
static constexpr size_t OFF_SCOREALL = 35782657;   // [5,N]

typedef short s16x8 __attribute__((ext_vector_type(8)));
typedef float f32x4 __attribute__((ext_vector_type(4)));
typedef unsigned int u32;
typedef unsigned short u16;

// packed bf16 weight offsets (u16 elems): [6][H][K] per layer (experts 0-4, shared=5)
static constexpr u32 O_T1 = 0,      O_T2 = 196608, O_T3 = 589824;
static constexpr u32 O_S1 = 774144, O_S2 = 872448;
// packed fp32 offsets (floats)
static constexpr u32 OB_T1 = 0, OB_T2 = 1536, OB_T3 = 3072, OB_S1 = 3792, OB_S2 = 4560;
static constexpr u32 OW_S3 = 4944, OB_S3 = 5328;

__device__ __forceinline__ float gelu_f(float x) {
    return 0.5f * x * (1.0f + erff(x * 0.70710678118654752440f));
}
__device__ __forceinline__ float bf2f(u16 u) {
    return __uint_as_float(((u32)u) << 16);
}
__device__ __forceinline__ u16 f2bf(float v) {
    return ((__hip_bfloat16_raw)__float2bfloat16(v)).x;
}
__device__ __forceinline__ void gload16(const u16* g, u16* l) {
    __builtin_amdgcn_global_load_lds(
        (const __attribute__((address_space(1))) u32*)g,
        (__attribute__((address_space(3))) u32*)l, 16, 0, 0);
}
#define MFMA16(a, b, c) __builtin_amdgcn_mfma_f32_16x16x32_bf16(a, b, c, 0, 0, 0)

// swizzled LDS fragment read: logical (row r, 16B-chunk c) at byte r*RB*2 + (c^(r&7))*16
__device__ __forceinline__ s16x8 lds_frag(const u16* buf, int RBu16, int r, int c) {
    return *(const s16x8*)&buf[r * RBu16 + (((c ^ (r & 7))) << 3)];
}
// swizzled LDS bf16 scalar store at logical (row r, col)
__device__ __forceinline__ void lds_store_bf16(u16* buf, int RBu16, int r, int col, float v) {
    const int ch = (col >> 3) ^ (r & 7);
    buf[r * RBu16 + ch * 8 + (col & 7)] = f2bf(v);
}

// ---------------------------------------------------------------------------
// fp32 tile GEMM (router L1/L2 only; topk_idx needs fp32-exact logits).
// ---------------------------------------------------------------------------
template<bool GELU>
__global__ __launch_bounds__(256)
void mlp_gemm(const float* __restrict__ A, const float* __restrict__ W,
              const float* __restrict__ bias, float* __restrict__ C,
              int Kd, int H)
{
    __shared__ float As[16][128];
    __shared__ float Ws[16][132];

    const int tid  = threadIdx.x;
    const int tx   = tid & 15;
    const int ty   = tid >> 4;
    const int row0 = blockIdx.x * 128;
    const int col0 = blockIdx.y * 128;
    const int lm = tid >> 1;
    const int lk = (tid & 1) * 8;

    float acc[8][8] = {};

    for (int k0 = 0; k0 < Kd; k0 += 16) {
        const float* src = A + (size_t)(row0 + lm) * Kd + k0 + lk;
        float4 f0 = *(const float4*)src;
        float4 f1 = *(const float4*)(src + 4);
        As[lk + 0][lm] = f0.x; As[lk + 1][lm] = f0.y;
        As[lk + 2][lm] = f0.z; As[lk + 3][lm] = f0.w;
        As[lk + 4][lm] = f1.x; As[lk + 5][lm] = f1.y;
        As[lk + 6][lm] = f1.z; As[lk + 7][lm] = f1.w;
        {
            const float* wsrc = W + (size_t)(k0 + ty) * H + col0 + tx * 8;
            float4 g0 = *(const float4*)wsrc;
            float4 g1 = *(const float4*)(wsrc + 4);
            *(float4*)&Ws[ty][tx * 8]     = g0;
            *(float4*)&Ws[ty][tx * 8 + 4] = g1;
        }
        __syncthreads();
        #pragma unroll
        for (int kk = 0; kk < 16; ++kk) {
            float a[8], w[8];
            *(float4*)&a[0] = *(const float4*)&As[kk][ty * 8];
            *(float4*)&a[4] = *(const float4*)&As[kk][ty * 8 + 4];
            *(float4*)&w[0] = *(const float4*)&Ws[kk][tx * 8];
            *(float4*)&w[4] = *(const float4*)&Ws[kk][tx * 8 + 4];
            #pragma unroll
            for (int i = 0; i < 8; ++i)
                #pragma unroll
                for (int j = 0; j < 8; ++j)
                    acc[i][j] = fmaf(a[i], w[j], acc[i][j]);
        }
        __syncthreads();
    }

    #pragma unroll
    for (int i = 0; i < 8; ++i) {
        const int r = row0 + ty * 8 + i;
        #pragma unroll
        for (int j = 0; j < 8; ++j) {
            const int c = col0 + tx * 8 + j;
            float v = acc[i][j] + bias[c];
            if (GELU) v = gelu_f(v);
            C[(size_t)r * H + c] = v;
        }
    }
}

// ---------------------------------------------------------------------------
// Router L3 + softmax partials + top-2 + gate-weight table (fused).
// ---------------------------------------------------------------------------
__global__ __launch_bounds__(256)
void router_l3post(const float* __restrict__ rh2, const float* __restrict__ w3,
                   const float* __restrict__ b3, float* __restrict__ logits,
                   float* __restrict__ oidx, float* __restrict__ wtok,
                   float* __restrict__ part)
{
    __shared__ float w3s[640];
    __shared__ float red[256];
    const int tid = threadIdx.x;
    for (int i = tid; i < 640; i += 256) w3s[i] = w3[i];
    __syncthreads();

    const int n = blockIdx.x * 256 + tid;
    const float* h = rh2 + (size_t)n * 128;

    float l[5];
    #pragma unroll
    for (int e = 0; e < 5; ++e) l[e] = b3[e];
    for (int k = 0; k < 128; k += 4) {
        float4 hv = *(const float4*)(h + k);
        #pragma unroll
        for (int e = 0; e < 5; ++e) {
            l[e] = fmaf(hv.x, w3s[(k + 0) * 5 + e], l[e]);
            l[e] = fmaf(hv.y, w3s[(k + 1) * 5 + e], l[e]);
            l[e] = fmaf(hv.z, w3s[(k + 2) * 5 + e], l[e]);
            l[e] = fmaf(hv.w, w3s[(k + 3) * 5 + e], l[e]);
        }
    }
    #pragma unroll
    for (int e = 0; e < 5; ++e) logits[(size_t)n * 5 + e] = l[e];

    // full softmax (aux loss partials)
    float m = l[0];
    #pragma unroll
    for (int e = 1; e < 5; ++e) m = fmaxf(m, l[e]);
    float p[5], s = 0.f;
    #pragma unroll
    for (int e = 0; e < 5; ++e) { p[e] = expf(l[e] - m); s += p[e]; }
    const float inv = 1.0f / s;

    #pragma unroll
    for (int e = 0; e < 5; ++e) {
        red[tid] = p[e] * inv;
        __syncthreads();
        for (int off = 128; off > 0; off >>= 1) {
            if (tid < off) red[tid] += red[tid + off];
            __syncthreads();
        }
        if (tid == 0) part[blockIdx.x * 5 + e] = red[0];
        __syncthreads();
    }

    // top-2 (ties keep lower index, matching jax.lax.top_k)
    int i0 = 0; float v0 = l[0];
    #pragma unroll
    for (int e = 1; e < 5; ++e) if (l[e] > v0) { v0 = l[e]; i0 = e; }
    int i1 = -1; float v1 = -1e30f;
    #pragma unroll
    for (int e = 0; e < 5; ++e) if (e != i0 && l[e] > v1) { v1 = l[e]; i1 = e; }

    const float t  = expf(v1 - v0);
    const float q0 = 1.0f / (1.0f + t);
    const float q1 = t / (1.0f + t);

    oidx[(size_t)n * 2]     = (float)i0;
    oidx[(size_t)n * 2 + 1] = (float)i1;
    #pragma unroll
    for (int e = 0; e < 5; ++e)
        wtok[(size_t)e * N_TOK + n] = 0.7f * (e == i0 ? q0 : (e == i1 ? q1 : 0.0f));
}

__global__ __launch_bounds__(256)
void aux_kernel(const float* __restrict__ part, float* __restrict__ aux)
{
    __shared__ float avg[5];
    const int tid = threadIdx.x;
    if (tid < 5) {
        float s = 0.f;
        for (int b = 0; b < 192; ++b) s += part[b * 5 + tid];
        avg[tid] = s / (float)N_TOK;
    }
    __syncthreads();
    if (tid == 0) {
        float ent = 0.f, l2 = 0.f;
        #pragma unroll
        for (int e = 0; e < 5; ++e) {
            ent -= avg[e] * logf(avg[e] + 1e-8f);
            float d = avg[e] - 0.2f;
            l2 += d * d;
        }
        l2 *= (1.0f / 5.0f);
        aux[0] = -ent * 0.01f + 0.01f * l2;
    }
}

// ---------------------------------------------------------------------------
// Fully fused expert kernel. One block = 64 tokens, 8 waves (512 thr).
// Per expert e in {0..4 unshared, 5 shared}:
//   traj: x[64,128] -> h1[64,256] -> h2[64,256] -> traj[64,120]
//   score: x -> s1[64,128] -> s2[64,64] -> score[64]
// Accumulates final = sum_e wgt_e * out_e in registers (wgt from wtok, 0.3 shared).
// LDS: xs 16KB + h1 32KB + h2 32KB = 80KB -> 2 blocks/CU.
// Weights read as B-fragments straight from global (L2-resident).
// ---------------------------------------------------------------------------
__global__ __launch_bounds__(512, 4)
void expert_fused(const u16* __restrict__ xb, const u16* __restrict__ wtb,
                  const float* __restrict__ biasp, const float* __restrict__ wtok,
                  float* __restrict__ out)
{
    __shared__ u16 xs[64 * 128];   // 16 KB, RB=128 (16 chunks), swizzled
    __shared__ u16 h1[64 * 256];   // 32 KB, RB=256 traj / RB=128 as s1
    __shared__ u16 h2[64 * 256];   // 32 KB, RB=256 traj / RB=64 as s2

    const int tid  = threadIdx.x;
    const int lane = tid & 63;
    const int wave = tid >> 6;         // 0..7
    const int row0 = blockIdx.x * 64;
    const int frow = lane & 15;        // fragment row/col within 16
    const int kgrp = lane >> 4;        // 0..3 k sub-chunk

    // ---- stage x tile: 1024 16B-chunks, pre-swizzled global source ----
    #pragma unroll
    for (int i = 0; i < 2; ++i) {
        const int idx = i * 512 + tid;
        const int r = idx >> 4, c = idx & 15;
        gload16(xb + (size_t)(row0 + r) * 128 + ((c ^ (r & 7)) << 3), &xs[idx * 8]);
    }

    float facc[4][4] = {};   // final traj acc: this wave's col = wave*16+frow
    float fscore = 0.f;      // final score acc (lanes with (lane&7)==0)

    __syncthreads();         // xs ready (barrier drains vmcnt)

    #pragma unroll 1
    for (int e = 0; e < 6; ++e) {
        // ================= trajectory L1: xs[64,128] -> h1[64,256] =========
        {
            const u16* w1 = wtb + O_T1 + e * 32768;        // [256][128]
            const float* b1 = biasp + OB_T1 + e * 256;
            const int c0 = wave * 32;
            f32x4 acc[4][2] = {};
            #pragma unroll
            for (int ks = 0; ks < 4; ++ks) {
                s16x8 b[2];
                #pragma unroll
                for (int n = 0; n < 2; ++n)
                    b[n] = *(const s16x8*)&w1[(size_t)(c0 + n * 16 + frow) * 128 + ks * 32 + kgrp * 8];
                #pragma unroll
                for (int m = 0; m < 4; ++m) {
                    s16x8 a = lds_frag(xs, 128, m * 16 + frow, ks * 4 + kgrp);
                    #pragma unroll
                    for (int n = 0; n < 2; ++n)
                        acc[m][n] = MFMA16(a, b[n], acc[m][n]);
                }
            }
            #pragma unroll
            for (int n = 0; n < 2; ++n) {
                const int col = c0 + n * 16 + frow;
                const float bb = b1[col];
                #pragma unroll
                for (int m = 0; m < 4; ++m)
                    #pragma unroll
                    for (int j = 0; j < 4; ++j)
                        lds_store_bf16(h1, 256, m * 16 + kgrp * 4 + j, col,
                                       gelu_f(acc[m][n][j] + bb));
            }
        }
        __syncthreads();   // B1: h1 complete

        // ================= trajectory L2: h1 -> h2 [64,256], K=256 =========
        {
            const u16* w2 = wtb + O_T2 + e * 65536;        // [256][256]
            const float* b2 = biasp + OB_T2 + e * 256;
            const int c0 = wave * 32;
            f32x4 acc[4][2] = {};
            #pragma unroll
            for (int ks = 0; ks < 8; ++ks) {
                s16x8 b[2];
                #pragma unroll
                for (int n = 0; n < 2; ++n)
                    b[n] = *(const s16x8*)&w2[(size_t)(c0 + n * 16 + frow) * 256 + ks * 32 + kgrp * 8];
                #pragma unroll
                for (int m = 0; m < 4; ++m) {
                    s16x8 a = lds_frag(h1, 256, m * 16 + frow, ks * 4 + kgrp);
                    #pragma unroll
                    for (int n = 0; n < 2; ++n)
                        acc[m][n] = MFMA16(a, b[n], acc[m][n]);
                }
            }
            #pragma unroll
            for (int n = 0; n < 2; ++n) {
                const int col = c0 + n * 16 + frow;
                const float bb = b2[col];
                #pragma unroll
                for (int m = 0; m < 4; ++m)
                    #pragma unroll
                    for (int j = 0; j < 4; ++j)
                        lds_store_bf16(h2, 256, m * 16 + kgrp * 4 + j, col,
                                       gelu_f(acc[m][n][j] + bb));
            }
        }
        __syncthreads();   // B2: h2 complete (h1 free)

        // ================= trajectory L3: h2 -> traj [64,120], K=256 =======
        {
            const u16* w3 = wtb + O_T3 + e * 30720;        // [120][256]
            const float* b3 = biasp + OB_T3 + e * 120;
            const int col = wave * 16 + frow;              // 0..127
            const bool valid = col < 120;
            const int colc = valid ? col : 119;
            f32x4 acc3[4] = {};
            #pragma unroll
            for (int ks = 0; ks < 8; ++ks) {
                s16x8 b = *(const s16x8*)&w3[(size_t)colc * 256 + ks * 32 + kgrp * 8];
                #pragma unroll
                for (int m = 0; m < 4; ++m) {
                    s16x8 a = lds_frag(h2, 256, m * 16 + frow, ks * 4 + kgrp);
                    acc3[m] = MFMA16(a, b, acc3[m]);
                }
            }
            const float bb = b3[colc];
            if (valid) {
                #pragma unroll
                for (int m = 0; m < 4; ++m)
                    #pragma unroll
                    for (int j = 0; j < 4; ++j) {
                        const int r = m * 16 + kgrp * 4 + j;
                        const float v = acc3[m][j] + bb;
                        const float wgt = (e < 5) ? wtok[(size_t)e * N_TOK + row0 + r] : 0.3f;
                        if (e < 5)
                            out[OFF_TRAJALL + ((size_t)e * N_TOK + row0 + r) * 120 + col] = v;
                        facc[m][j] = fmaf(wgt, v, facc[m][j]);
                    }
            }
        }

        // ================= score S1: xs -> s1 (h1 region, RB=128) ==========
        {
            const u16* w1s = wtb + O_S1 + e * 16384;       // [128][128]
            const float* b1s = biasp + OB_S1 + e * 128;
            const int col = wave * 16 + frow;              // 0..127
            f32x4 acc[4] = {};
            #pragma unroll
            for (int ks = 0; ks < 4; ++ks) {
                s16x8 b = *(const s16x8*)&w1s[(size_t)col * 128 + ks * 32 + kgrp * 8];
                #pragma unroll
                for (int m = 0; m < 4; ++m) {
                    s16x8 a = lds_frag(xs, 128, m * 16 + frow, ks * 4 + kgrp);
                    acc[m] = MFMA16(a, b, acc[m]);
                }
            }
            const float bb = b1s[col];
            #pragma unroll
            for (int m = 0; m < 4; ++m)
                #pragma unroll
                for (int j = 0; j < 4; ++j)
                    lds_store_bf16(h1, 128, m * 16 + kgrp * 4 + j, col,
                                   gelu_f(acc[m][j] + bb));
        }
        __syncthreads();   // B3: s1 complete; L3's h2 reads done

        // ================= score S2: s1 -> s2 (h2 region, RB=64) ===========
        if (wave < 4) {
            const u16* w2s = wtb + O_S2 + e * 8192;        // [64][128]
            const float* b2s = biasp + OB_S2 + e * 64;
            const int col = wave * 16 + frow;              // 0..63
            f32x4 acc[4] = {};
            #pragma unroll
            for (int ks = 0; ks < 4; ++ks) {
                s16x8 b = *(const s16x8*)&w2s[(size_t)col * 128 + ks * 32 + kgrp * 8];
                #pragma unroll
                for (int m = 0; m < 4; ++m) {
                    s16x8 a = lds_frag(h1, 128, m * 16 + frow, ks * 4 + kgrp);
                    acc[m] = MFMA16(a, b, acc[m]);
                }
            }
            const float bb = b2s[col];
            #pragma unroll
            for (int m = 0; m < 4; ++m)
                #pragma unroll
                for (int j = 0; j < 4; ++j)
                    lds_store_bf16(h2, 64, m * 16 + kgrp * 4 + j, col,
                                   gelu_f(acc[m][j] + bb));
        }
        __syncthreads();   // B4: s2 complete; s1 reads done

        // ================= score S3: s2 -> score (dot64) ====================
        {
            const float* w3s = biasp + OW_S3 + e * 64;
            const int tok = wave * 8 + (lane >> 3);
            const int kc  = lane & 7;
            s16x8 sv = lds_frag(h2, 64, tok, kc);
            float4 wA = *(const float4*)&w3s[kc * 8];
            float4 wB = *(const float4*)&w3s[kc * 8 + 4];
            float p = 0.f;
            p = fmaf(bf2f((u16)sv[0]), wA.x, p);
            p = fmaf(bf2f((u16)sv[1]), wA.y, p);
            p = fmaf(bf2f((u16)sv[2]), wA.z, p);
            p = fmaf(bf2f((u16)sv[3]), wA.w, p);
            p = fmaf(bf2f((u16)sv[4]), wB.x, p);
            p = fmaf(bf2f((u16)sv[5]), wB.y, p);
            p = fmaf(bf2f((u16)sv[6]), wB.z, p);
            p = fmaf(bf2f((u16)sv[7]), wB.w, p);
            p += __shfl_xor(p, 1);
            p += __shfl_xor(p, 2);
            p += __shfl_xor(p, 4);
            if (kc == 0) {
                const float val = p + biasp[OB_S3 + e];
                const float wgt = (e < 5) ? wtok[(size_t)e * N_TOK + row0 + tok] : 0.3f;
                if (e < 5)
                    out[OFF_SCOREALL + (size_t)e * N_TOK + row0 + tok] = val;
                fscore = fmaf(wgt, val, fscore);
            }
        }
        // next-iter L1 overwrites h1: safe (B4 passed; S3 touches only h2)
    }

    // ---- final combined outputs ----
    {
        const int col = wave * 16 + frow;
        if (col < 120) {
            #pragma unroll
            for (int m = 0; m < 4; ++m)
                #pragma unroll
                for (int j = 0; j < 4; ++j) {
                    const int r = m * 16 + kgrp * 4 + j;
                    out[OFF_TRAJ + (size_t)(row0 + r) * 120 + col] = facc[m][j];
                }
        }
        const int tok = wave * 8 + (lane >> 3);
        if ((lane & 7) == 0)
            out[OFF_SCORE + row0 + tok] = fscore;
    }
}

// ---------------------------------------------------------------------------
__global__ __launch_bounds__(256)
void convert_x(const float* __restrict__ x, u16* __restrict__ xb)
{
    const size_t i = ((size_t)blockIdx.x * 256 + threadIdx.x) * 4;
    float4 v = *(const float4*)(x + i);
    ushort4 o;
    o.x = f2bf(v.x); o.y = f2bf(v.y); o.z = f2bf(v.z); o.w = f2bf(v.w);
    *(ushort4*)(xb + i) = o;
}

// Weight convert+transpose: src fp32 [nz][K][H] -> dst bf16 [nz][H][K]
struct WDesc { const float* src; u32 dstOff; int K, H, nz; };
struct WTable { WDesc d[10]; };

__global__ __launch_bounds__(256)
void convert_w(WTable t, u16* __restrict__ dst)
{
    const WDesc dd = t.d[blockIdx.y];
    const int total = dd.K * dd.H * dd.nz;
    const int idx = blockIdx.x * 256 + threadIdx.x;
    if (idx < total) {
        const int kh = dd.K * dd.H;
        const int e = idx / kh;
        const int r = idx - e * kh;
        const int h = r / dd.K;
        const int k = r - h * dd.K;
        const float v = dd.src[(size_t)e * kh + (size_t)k * dd.H + h];
        dst[dd.dstOff + idx] = f2bf(v);
    }
}

// Flat fp32 gather-pack (biases + score L3 weights)
struct CDesc { const float* src; u32 dstOff; u32 n; };
struct CTable { CDesc d[14]; };

__global__ __launch_bounds__(256)
void pack_f32(CTable t, float* __restrict__ dst)
{
    const CDesc dd = t.d[blockIdx.y];
    const u32 i = blockIdx.x * 256 + threadIdx.x;
    if (i < dd.n) dst[dd.dstOff + i] = dd.src[i];
}

// ---------------------------------------------------------------------------
extern "C" void kernel_launch(void* const* d_in, const int* in_sizes, int n_in,
                              void* d_out, int out_size, void* d_ws, size_t ws_size,
                              hipStream_t stream)
{
    (void)in_sizes; (void)n_in; (void)out_size; (void)ws_size;

    const float* x   = (const float*)d_in[0];
    const float* rw1 = (const float*)d_in[1];
    const float* rb1 = (const float*)d_in[2];
    const float* rw2 = (const float*)d_in[3];
    const float* rb2 = (const float*)d_in[4];
    const float* rw3 = (const float*)d_in[5];
    const float* rb3 = (const float*)d_in[6];

    float* out = (float*)d_out;
    char* ws = (char*)d_ws;

    // ---- workspace layout ----
    u16*   xb    = (u16*)(ws);                  // [N,128] bf16        12,582,912 B
    u16*   wtb   = (u16*)(ws + 12582912);       // packed bf16 W        1,843,200 B
    float* biasp = (float*)(ws + 14426368);     // packed fp32             21,336 B
    float* part  = (float*)(ws + 14447744);     // [192,5]
    float* wtok  = (float*)(ws + 14451712);     // [5][N] gate weights    983,040 B
    float* rh1   = (float*)(ws + 15434752);     // [N,256] fp32        50,331,648 B
    float* rh2   = (float*)(ws + 65766400);     // [N,128] fp32        25,165,824 B

    const dim3 blk(256);

    // ---- router (fp32: topk_idx must match reference ordering exactly) ----
    mlp_gemm<true ><<<dim3(N_TOK / 128, 2), blk, 0, stream>>>(x,   rw1, rb1, rh1, 128, 256);
    mlp_gemm<true ><<<dim3(N_TOK / 128, 1), blk, 0, stream>>>(rh1, rw2, rb2, rh2, 256, 128);
    router_l3post<<<dim3(N_TOK / 256), blk, 0, stream>>>(
        rh2, rw3, rb3, out + OFF_LOGITS, out + OFF_IDX, wtok, part);
    aux_kernel<<<dim3(1), blk, 0, stream>>>(part, out + OFF_AUX);

    // ---- conversions / packing ----
    convert_x<<<dim3(N_TOK * 128 / 1024), blk, 0, stream>>>(x, xb);
    {
        WTable t;
        t.d[0] = { (const float*)d_in[19], O_T1,              128, 256, 5 };
        t.d[1] = { (const float*)d_in[7],  O_T1 + 5 * 32768,  128, 256, 1 };
        t.d[2] = { (const float*)d_in[21], O_T2,              256, 256, 5 };
        t.d[3] = { (const float*)d_in[9],  O_T2 + 5 * 65536,  256, 256, 1 };
        t.d[4] = { (const float*)d_in[23], O_T3,              256, 120, 5 };
        t.d[5] = { (const float*)d_in[11], O_T3 + 5 * 30720,  256, 120, 1 };
        t.d[6] = { (const float*)d_in[25], O_S1,              128, 128, 5 };
        t.d[7] = { (const float*)d_in[13], O_S1 + 5 * 16384,  128, 128, 1 };
        t.d[8] = { (const float*)d_in[27], O_S2,              128,  64, 5 };
        t.d[9] = { (const float*)d_in[15], O_S2 + 5 * 8192,   128,  64, 1 };
        convert_w<<<dim3(1280, 10), blk, 0, stream>>>(t, wtb);
    }
    {
        CTable t;
        t.d[0]  = { (const float*)d_in[20], OB_T1,        1280 };
        t.d[1]  = { (const float*)d_in[8],  OB_T1 + 1280,  256 };
        t.d[2]  = { (const float*)d_in[22], OB_T2,        1280 };
        t.d[3]  = { (const float*)d_in[10], OB_T2 + 1280,  256 };
        t.d[4]  = { (const float*)d_in[24], OB_T3,         600 };
        t.d[5]  = { (const float*)d_in[12], OB_T3 + 600,   120 };
        t.d[6]  = { (const float*)d_in[26], OB_S1,         640 };
        t.d[7]  = { (const float*)d_in[14], OB_S1 + 640,   128 };
        t.d[8]  = { (const float*)d_in[28], OB_S2,         320 };
        t.d[9]  = { (const float*)d_in[16], OB_S2 + 320,    64 };
        t.d[10] = { (const float*)d_in[29], OW_S3,         320 };
        t.d[11] = { (const float*)d_in[17], OW_S3 + 320,    64 };
        t.d[12] = { (const float*)d_in[30], OB_S3,           5 };
        t.d[13] = { (const float*)d_in[18], OB_S3 + 5,       1 };
        pack_f32<<<dim3(5, 14), blk, 0, stream>>>(t, biasp);
    }

    // ---- fused experts + in-register top-k combine ----
    expert_fused<<<dim3(N_TOK / 64), dim3(512), 0, stream>>>(xb, wtb, biasp, wtok, out);
}

// Round 5
// 543.414 us; speedup vs baseline: 1.5764x; 1.5764x over previous
//
#include <hip/hip_runtime.h>
#include <hip/hip_bf16.h>
#include <cstdint>
#include <cstddef>

// Problem constants
static constexpr int N_TOK = 49152;     // B*M = 8192*6
// d_out offsets (floats), outputs concatenated in reference return order
static constexpr size_t OFF_TRAJ     = 0;          // [N,120]
static constexpr size_t OFF_SCORE    = 5898240;    // [N]
static constexpr size_t OFF_LOGITS   = 5947392;    // [N,5]
static constexpr size_t OFF_IDX      = 6193152;    // [N,2]  (ints stored as floats)
static constexpr size_t OFF_AUX      = 6291456;    // [1]
static constexpr size_t OFF_TRAJALL  = 6291457;    // [5,N,120]
static constexpr size_t OFF_SCOREALL = 35782657;   // [5,N]

typedef short s16x8 __attribute__((ext_vector_type(8)));
typedef float f32x4 __attribute__((ext_vector_type(4)));
typedef f32x4 f32x4u __attribute__((aligned(4)));   // reduced-alignment variant
typedef unsigned int u32;
typedef unsigned short u16;

// packed bf16 weight offsets (u16 elems): [6][H][K] per layer (experts 0-4, shared=5)
static constexpr u32 O_T1 = 0,      O_T2 = 196608, O_T3 = 589824;
static constexpr u32 O_S1 = 774144, O_S2 = 872448;
// packed fp32 offsets (floats)
static constexpr u32 OB_T1 = 0, OB_T2 = 1536, OB_T3 = 3072, OB_S1 = 3792, OB_S2 = 4560;
static constexpr u32 OW_S3 = 4944, OB_S3 = 5328;

__device__ __forceinline__ float gelu_f(float x) {
    return 0.5f * x * (1.0f + erff(x * 0.70710678118654752440f));
}
__device__ __forceinline__ float bf2f(u16 u) {
    return __uint_as_float(((u32)u) << 16);
}
__device__ __forceinline__ u16 f2bf(float v) {
    return ((__hip_bfloat16_raw)__float2bfloat16(v)).x;
}
__device__ __forceinline__ void gload16(const u16* g, u16* l) {
    __builtin_amdgcn_global_load_lds(
        (const __attribute__((address_space(1))) u32*)g,
        (__attribute__((address_space(3))) u32*)l, 16, 0, 0);
}
#define MFMA16(a, b, c) __builtin_amdgcn_mfma_f32_16x16x32_bf16(a, b, c, 0, 0, 0)

// swizzled LDS fragment read: logical (row r, 16B-chunk c) at chunk slot c^(r&7)
__device__ __forceinline__ s16x8 lds_frag(const u16* buf, int RBu16, int r, int c) {
    return *(const s16x8*)&buf[r * RBu16 + ((c ^ (r & 7)) << 3)];
}
// swizzled 8B LDS store of 4 consecutive bf16 cols (colb % 4 == 0, colb&7 in {0,4})
__device__ __forceinline__ void lds_store4(u16* buf, int RBu16, int r, int colb,
                                           float v0, float v1, float v2, float v3) {
    const int ch = (colb >> 3) ^ (r & 7);
    ushort4 st = { f2bf(v0), f2bf(v1), f2bf(v2), f2bf(v3) };
    *(ushort4*)&buf[r * RBu16 + ch * 8 + (colb & 7)] = st;
}
__device__ __forceinline__ void nt_store4(float* p, f32x4 v) {
    __builtin_nontemporal_store(v, (f32x4*)p);      // 16B-aligned path
}
__device__ __forceinline__ void nt_store4u(float* p, f32x4 v) {
    __builtin_nontemporal_store(v, (f32x4u*)p);     // 4B-aligned path (odd base)
}

// ---------------------------------------------------------------------------
// fp32 tile GEMM (router L1/L2 only; topk_idx needs fp32-exact logits).
// ---------------------------------------------------------------------------
template<bool GELU>
__global__ __launch_bounds__(256)
void mlp_gemm(const float* __restrict__ A, const float* __restrict__ W,
              const float* __restrict__ bias, float* __restrict__ C,
              int Kd, int H)
{
    __shared__ float As[16][128];
    __shared__ float Ws[16][132];

    const int tid  = threadIdx.x;
    const int tx   = tid & 15;
    const int ty   = tid >> 4;
    const int row0 = blockIdx.x * 128;
    const int col0 = blockIdx.y * 128;
    const int lm = tid >> 1;
    const int lk = (tid & 1) * 8;

    float acc[8][8] = {};

    for (int k0 = 0; k0 < Kd; k0 += 16) {
        const float* src = A + (size_t)(row0 + lm) * Kd + k0 + lk;
        float4 f0 = *(const float4*)src;
        float4 f1 = *(const float4*)(src + 4);
        As[lk + 0][lm] = f0.x; As[lk + 1][lm] = f0.y;
        As[lk + 2][lm] = f0.z; As[lk + 3][lm] = f0.w;
        As[lk + 4][lm] = f1.x; As[lk + 5][lm] = f1.y;
        As[lk + 6][lm] = f1.z; As[lk + 7][lm] = f1.w;
        {
            const float* wsrc = W + (size_t)(k0 + ty) * H + col0 + tx * 8;
            float4 g0 = *(const float4*)wsrc;
            float4 g1 = *(const float4*)(wsrc + 4);
            *(float4*)&Ws[ty][tx * 8]     = g0;
            *(float4*)&Ws[ty][tx * 8 + 4] = g1;
        }
        __syncthreads();
        #pragma unroll
        for (int kk = 0; kk < 16; ++kk) {
            float a[8], w[8];
            *(float4*)&a[0] = *(const float4*)&As[kk][ty * 8];
            *(float4*)&a[4] = *(const float4*)&As[kk][ty * 8 + 4];
            *(float4*)&w[0] = *(const float4*)&Ws[kk][tx * 8];
            *(float4*)&w[4] = *(const float4*)&Ws[kk][tx * 8 + 4];
            #pragma unroll
            for (int i = 0; i < 8; ++i)
                #pragma unroll
                for (int j = 0; j < 8; ++j)
                    acc[i][j] = fmaf(a[i], w[j], acc[i][j]);
        }
        __syncthreads();
    }

    #pragma unroll
    for (int i = 0; i < 8; ++i) {
        const int r = row0 + ty * 8 + i;
        #pragma unroll
        for (int j = 0; j < 8; ++j) {
            const int c = col0 + tx * 8 + j;
            float v = acc[i][j] + bias[c];
            if (GELU) v = gelu_f(v);
            C[(size_t)r * H + c] = v;
        }
    }
}

// ---------------------------------------------------------------------------
// Router L3 + softmax partials + top-2 + gate-weight table (fused).
// ---------------------------------------------------------------------------
__global__ __launch_bounds__(256)
void router_l3post(const float* __restrict__ rh2, const float* __restrict__ w3,
                   const float* __restrict__ b3, float* __restrict__ logits,
                   float* __restrict__ oidx, float* __restrict__ wtok,
                   float* __restrict__ part)
{
    __shared__ float w3s[640];
    __shared__ float red[256];
    const int tid = threadIdx.x;
    for (int i = tid; i < 640; i += 256) w3s[i] = w3[i];
    __syncthreads();

    const int n = blockIdx.x * 256 + tid;
    const float* h = rh2 + (size_t)n * 128;

    float l[5];
    #pragma unroll
    for (int e = 0; e < 5; ++e) l[e] = b3[e];
    for (int k = 0; k < 128; k += 4) {
        float4 hv = *(const float4*)(h + k);
        #pragma unroll
        for (int e = 0; e < 5; ++e) {
            l[e] = fmaf(hv.x, w3s[(k + 0) * 5 + e], l[e]);
            l[e] = fmaf(hv.y, w3s[(k + 1) * 5 + e], l[e]);
            l[e] = fmaf(hv.z, w3s[(k + 2) * 5 + e], l[e]);
            l[e] = fmaf(hv.w, w3s[(k + 3) * 5 + e], l[e]);
        }
    }
    #pragma unroll
    for (int e = 0; e < 5; ++e) logits[(size_t)n * 5 + e] = l[e];

    // full softmax (aux loss partials)
    float m = l[0];
    #pragma unroll
    for (int e = 1; e < 5; ++e) m = fmaxf(m, l[e]);
    float p[5], s = 0.f;
    #pragma unroll
    for (int e = 0; e < 5; ++e) { p[e] = expf(l[e] - m); s += p[e]; }
    const float inv = 1.0f / s;

    #pragma unroll
    for (int e = 0; e < 5; ++e) {
        red[tid] = p[e] * inv;
        __syncthreads();
        for (int off = 128; off > 0; off >>= 1) {
            if (tid < off) red[tid] += red[tid + off];
            __syncthreads();
        }
        if (tid == 0) part[blockIdx.x * 5 + e] = red[0];
        __syncthreads();
    }

    // top-2 (ties keep lower index, matching jax.lax.top_k)
    int i0 = 0; float v0 = l[0];
    #pragma unroll
    for (int e = 1; e < 5; ++e) if (l[e] > v0) { v0 = l[e]; i0 = e; }
    int i1 = -1; float v1 = -1e30f;
    #pragma unroll
    for (int e = 0; e < 5; ++e) if (e != i0 && l[e] > v1) { v1 = l[e]; i1 = e; }

    const float t  = expf(v1 - v0);
    const float q0 = 1.0f / (1.0f + t);
    const float q1 = t / (1.0f + t);

    oidx[(size_t)n * 2]     = (float)i0;
    oidx[(size_t)n * 2 + 1] = (float)i1;
    #pragma unroll
    for (int e = 0; e < 5; ++e)
        wtok[(size_t)e * N_TOK + n] = 0.7f * (e == i0 ? q0 : (e == i1 ? q1 : 0.0f));
}

__global__ __launch_bounds__(256)
void aux_kernel(const float* __restrict__ part, float* __restrict__ aux)
{
    __shared__ float avg[5];
    const int tid = threadIdx.x;
    if (tid < 5) {
        float s = 0.f;
        for (int b = 0; b < 192; ++b) s += part[b * 5 + tid];
        avg[tid] = s / (float)N_TOK;
    }
    __syncthreads();
    if (tid == 0) {
        float ent = 0.f, l2 = 0.f;
        #pragma unroll
        for (int e = 0; e < 5; ++e) {
            ent -= avg[e] * logf(avg[e] + 1e-8f);
            float d = avg[e] - 0.2f;
            l2 += d * d;
        }
        l2 *= (1.0f / 5.0f);
        aux[0] = -ent * 0.01f + 0.01f * l2;
    }
}

// ---------------------------------------------------------------------------
// Fused trajectory path: x -> h1 -> h2 -> traj for 6 experts, 64-token blocks,
// 8 waves. Swapped-operand MFMA (D = [hcol][token]) so every store is
// vectorized. Weight fragments register-prefetched one stage ahead.
// Final combined traj accumulated in registers (gates from wtok; 0.3 shared).
// LDS 80 KB -> 2 blocks/CU (16 waves). 2 barriers per expert.
// ---------------------------------------------------------------------------
__global__ __launch_bounds__(512, 4)
void expert_traj(const u16* __restrict__ xb, const u16* __restrict__ wtb,
                 const float* __restrict__ biasp, const float* __restrict__ wtok,
                 float* __restrict__ out)
{
    __shared__ u16 xs[64 * 128];   // 16 KB
    __shared__ u16 h1[64 * 256];   // 32 KB
    __shared__ u16 h2[64 * 256];   // 32 KB

    const int tid  = threadIdx.x;
    const int lane = tid & 63;
    const int wave = tid >> 6;          // 0..7
    const int row0 = blockIdx.x * 64;
    const int frow = lane & 15;
    const int kgrp = lane >> 4;         // 0..3
    const int c0   = wave * 32;         // L1/L2 col slice

    // stage x tile (linear LDS dest, inverse-swizzled global source)
    #pragma unroll
    for (int i = 0; i < 2; ++i) {
        const int idx = i * 512 + tid;
        const int r = idx >> 4, c = idx & 15;
        gload16(xb + (size_t)(row0 + r) * 128 + ((c ^ (r & 7)) << 3), &xs[idx * 8]);
    }

    const int col3 = wave * 16 + kgrp * 4;                       // L3 output colbase
    const int r3   = (wave * 16 + frow) < 120 ? (wave * 16 + frow) : 119;

    f32x4 facc[4] = {};   // final traj acc: [m tokens] x 4 cols

    // prefetch expert-0 L1 weight fragments
    s16x8 wf1[4][2];
    {
        const u16* w1p = wtb + O_T1;
        #pragma unroll
        for (int n = 0; n < 2; ++n) {
            const u16* p = w1p + (size_t)(c0 + n * 16 + frow) * 128 + kgrp * 8;
            #pragma unroll
            for (int ks = 0; ks < 4; ++ks) wf1[ks][n] = *(const s16x8*)(p + ks * 32);
        }
    }

    __syncthreads();   // xs ready (drains vmcnt)

    #pragma unroll 1
    for (int e = 0; e < 6; ++e) {
        float wg[4];
        #pragma unroll
        for (int m = 0; m < 4; ++m)
            wg[m] = (e < 5) ? wtok[(size_t)e * N_TOK + row0 + m * 16 + frow] : 0.3f;

        // ---------- L1: xs[64,128] -> h1[64,256] ----------
        f32x4 acc1[4][2] = {};
        #pragma unroll
        for (int ks = 0; ks < 4; ++ks)
            #pragma unroll
            for (int m = 0; m < 4; ++m) {
                const s16x8 a = lds_frag(xs, 128, m * 16 + frow, ks * 4 + kgrp);
                #pragma unroll
                for (int n = 0; n < 2; ++n)
                    acc1[m][n] = MFMA16(wf1[ks][n], a, acc1[m][n]);
            }

        // prefetch L2 first-half weights (hidden under stores+barrier)
        const u16* w2p = wtb + O_T2 + e * 65536;
        s16x8 wf2a[4][2];
        #pragma unroll
        for (int n = 0; n < 2; ++n) {
            const u16* p = w2p + (size_t)(c0 + n * 16 + frow) * 256 + kgrp * 8;
            #pragma unroll
            for (int ks = 0; ks < 4; ++ks) wf2a[ks][n] = *(const s16x8*)(p + ks * 32);
        }

        {   // store h1 (+bias+gelu): lane holds 4 consecutive cols -> 8B stores
            const float* b1 = biasp + OB_T1 + e * 256;
            #pragma unroll
            for (int n = 0; n < 2; ++n) {
                const int colb = c0 + n * 16 + kgrp * 4;
                const f32x4 bb = *(const f32x4*)&b1[colb];
                #pragma unroll
                for (int m = 0; m < 4; ++m)
                    lds_store4(h1, 256, m * 16 + frow, colb,
                               gelu_f(acc1[m][n][0] + bb[0]),
                               gelu_f(acc1[m][n][1] + bb[1]),
                               gelu_f(acc1[m][n][2] + bb[2]),
                               gelu_f(acc1[m][n][3] + bb[3]));
            }
        }
        __syncthreads();   // B1: h1 ready (also fences prior L3 h2-reads)

        // ---------- L2: h1 -> h2, K=256 ----------
        f32x4 acc2[4][2] = {};
        #pragma unroll
        for (int ks = 0; ks < 4; ++ks)
            #pragma unroll
            for (int m = 0; m < 4; ++m) {
                const s16x8 a = lds_frag(h1, 256, m * 16 + frow, ks * 4 + kgrp);
                #pragma unroll
                for (int n = 0; n < 2; ++n)
                    acc2[m][n] = MFMA16(wf2a[ks][n], a, acc2[m][n]);
            }
        s16x8 wf2b[4][2];
        #pragma unroll
        for (int n = 0; n < 2; ++n) {
            const u16* p = w2p + (size_t)(c0 + n * 16 + frow) * 256 + 128 + kgrp * 8;
            #pragma unroll
            for (int ks = 0; ks < 4; ++ks) wf2b[ks][n] = *(const s16x8*)(p + ks * 32);
        }
        #pragma unroll
        for (int ks = 0; ks < 4; ++ks)
            #pragma unroll
            for (int m = 0; m < 4; ++m) {
                const s16x8 a = lds_frag(h1, 256, m * 16 + frow, (ks + 4) * 4 + kgrp);
                #pragma unroll
                for (int n = 0; n < 2; ++n)
                    acc2[m][n] = MFMA16(wf2b[ks][n], a, acc2[m][n]);
            }

        {   // store h2 (+bias+gelu)
            const float* b2 = biasp + OB_T2 + e * 256;
            #pragma unroll
            for (int n = 0; n < 2; ++n) {
                const int colb = c0 + n * 16 + kgrp * 4;
                const f32x4 bb = *(const f32x4*)&b2[colb];
                #pragma unroll
                for (int m = 0; m < 4; ++m)
                    lds_store4(h2, 256, m * 16 + frow, colb,
                               gelu_f(acc2[m][n][0] + bb[0]),
                               gelu_f(acc2[m][n][1] + bb[1]),
                               gelu_f(acc2[m][n][2] + bb[2]),
                               gelu_f(acc2[m][n][3] + bb[3]));
            }
        }
        __syncthreads();   // B2: h2 ready

        // prefetch L3 weights + next-expert L1 weights (L3 MFMA hides wf1)
        s16x8 wf3[8];
        {
            const u16* w3p = wtb + O_T3 + e * 30720 + (size_t)r3 * 256 + kgrp * 8;
            #pragma unroll
            for (int ks = 0; ks < 8; ++ks) wf3[ks] = *(const s16x8*)(w3p + ks * 32);
        }
        if (e < 5) {
            const u16* w1p = wtb + O_T1 + (e + 1) * 32768;
            #pragma unroll
            for (int n = 0; n < 2; ++n) {
                const u16* p = w1p + (size_t)(c0 + n * 16 + frow) * 128 + kgrp * 8;
                #pragma unroll
                for (int ks = 0; ks < 4; ++ks) wf1[ks][n] = *(const s16x8*)(p + ks * 32);
            }
        }

        // ---------- L3: h2 -> traj[64,120] ----------
        f32x4 acc3[4] = {};
        #pragma unroll
        for (int ks = 0; ks < 8; ++ks)
            #pragma unroll
            for (int m = 0; m < 4; ++m) {
                const s16x8 a = lds_frag(h2, 256, m * 16 + frow, ks * 4 + kgrp);
                acc3[m] = MFMA16(wf3[ks], a, acc3[m]);
            }

        if (col3 < 120) {
            const float* b3 = biasp + OB_T3 + e * 120;
            const f32x4 bb = *(const f32x4*)&b3[col3];
            #pragma unroll
            for (int m = 0; m < 4; ++m) {
                f32x4 v;
                #pragma unroll
                for (int j = 0; j < 4; ++j) v[j] = acc3[m][j] + bb[j];
                if (e < 5)
                    nt_store4u(out + OFF_TRAJALL +
                               ((size_t)e * N_TOK + row0 + m * 16 + frow) * 120 + col3, v);
                #pragma unroll
                for (int j = 0; j < 4; ++j) facc[m][j] = fmaf(wg[m], v[j], facc[m][j]);
            }
        }
    }

    // final combined trajectory
    if (col3 < 120) {
        #pragma unroll
        for (int m = 0; m < 4; ++m)
            nt_store4(out + OFF_TRAJ + (size_t)(row0 + m * 16 + frow) * 120 + col3, facc[m]);
    }
}

// ---------------------------------------------------------------------------
// Fused score path: x -> s1 -> s2 -> score for 6 experts + combined score.
// 64-token blocks, 4 waves, LDS 40 KB -> 4 blocks/CU.
// ---------------------------------------------------------------------------
__global__ __launch_bounds__(256, 4)
void expert_score(const u16* __restrict__ xb, const u16* __restrict__ wtb,
                  const float* __restrict__ biasp, const float* __restrict__ wtok,
                  float* __restrict__ out)
{
    __shared__ u16 xs[64 * 128];   // 16 KB
    __shared__ u16 s1[64 * 128];   // 16 KB
    __shared__ u16 s2[64 * 64];    //  8 KB

    const int tid  = threadIdx.x;
    const int lane = tid & 63;
    const int wave = tid >> 6;      // 0..3
    const int row0 = blockIdx.x * 64;
    const int frow = lane & 15;
    const int kgrp = lane >> 4;
    const int c0   = wave * 32;

    #pragma unroll
    for (int i = 0; i < 4; ++i) {
        const int idx = i * 256 + tid;
        const int r = idx >> 4, c = idx & 15;
        gload16(xb + (size_t)(row0 + r) * 128 + ((c ^ (r & 7)) << 3), &xs[idx * 8]);
    }

    const int tok3 = wave * 16 + (lane >> 2);
    const int kc   = lane & 3;
    float fscore = 0.f;

    s16x8 wfa[4][2];
    {
        const u16* wp = wtb + O_S1;
        #pragma unroll
        for (int n = 0; n < 2; ++n) {
            const u16* p = wp + (size_t)(c0 + n * 16 + frow) * 128 + kgrp * 8;
            #pragma unroll
            for (int ks = 0; ks < 4; ++ks) wfa[ks][n] = *(const s16x8*)(p + ks * 32);
        }
    }

    __syncthreads();

    #pragma unroll 1
    for (int e = 0; e < 6; ++e) {
        const float wgs = (e < 5) ? wtok[(size_t)e * N_TOK + row0 + tok3] : 0.3f;

        // ---- S1: xs -> s1[64,128] ----
        f32x4 acc1[4][2] = {};
        #pragma unroll
        for (int ks = 0; ks < 4; ++ks)
            #pragma unroll
            for (int m = 0; m < 4; ++m) {
                const s16x8 a = lds_frag(xs, 128, m * 16 + frow, ks * 4 + kgrp);
                #pragma unroll
                for (int n = 0; n < 2; ++n)
                    acc1[m][n] = MFMA16(wfa[ks][n], a, acc1[m][n]);
            }
        // prefetch S2 weights
        s16x8 wfb[4];
        {
            const u16* p = wtb + O_S2 + e * 8192 + (size_t)(wave * 16 + frow) * 128 + kgrp * 8;
            #pragma unroll
            for (int ks = 0; ks < 4; ++ks) wfb[ks] = *(const s16x8*)(p + ks * 32);
        }
        {
            const float* b1 = biasp + OB_S1 + e * 128;
            #pragma unroll
            for (int n = 0; n < 2; ++n) {
                const int colb = c0 + n * 16 + kgrp * 4;
                const f32x4 bb = *(const f32x4*)&b1[colb];
                #pragma unroll
                for (int m = 0; m < 4; ++m)
                    lds_store4(s1, 128, m * 16 + frow, colb,
                               gelu_f(acc1[m][n][0] + bb[0]),
                               gelu_f(acc1[m][n][1] + bb[1]),
                               gelu_f(acc1[m][n][2] + bb[2]),
                               gelu_f(acc1[m][n][3] + bb[3]));
            }
        }
        __syncthreads();   // B1: s1 ready

        // ---- S2: s1 -> s2[64,64] ----
        f32x4 acc2[4] = {};
        #pragma unroll
        for (int ks = 0; ks < 4; ++ks)
            #pragma unroll
            for (int m = 0; m < 4; ++m) {
                const s16x8 a = lds_frag(s1, 128, m * 16 + frow, ks * 4 + kgrp);
                acc2[m] = MFMA16(wfb[ks], a, acc2[m]);
            }
        // prefetch next-expert S1 weights
        if (e < 5) {
            const u16* wp = wtb + O_S1 + (e + 1) * 16384;
            #pragma unroll
            for (int n = 0; n < 2; ++n) {
                const u16* p = wp + (size_t)(c0 + n * 16 + frow) * 128 + kgrp * 8;
                #pragma unroll
                for (int ks = 0; ks < 4; ++ks) wfa[ks][n] = *(const s16x8*)(p + ks * 32);
            }
        }
        {
            const int colb = wave * 16 + kgrp * 4;
            const float* b2 = biasp + OB_S2 + e * 64;
            const f32x4 bb = *(const f32x4*)&b2[colb];
            #pragma unroll
            for (int m = 0; m < 4; ++m)
                lds_store4(s2, 64, m * 16 + frow, colb,
                           gelu_f(acc2[m][0] + bb[0]),
                           gelu_f(acc2[m][1] + bb[1]),
                           gelu_f(acc2[m][2] + bb[2]),
                           gelu_f(acc2[m][3] + bb[3]));
        }
        __syncthreads();   // B2: s2 ready

        // ---- S3: dot64 per token ----
        {
            const float* w3 = biasp + OW_S3 + e * 64 + kc * 16;
            const s16x8 va = lds_frag(s2, 64, tok3, kc * 2);
            const s16x8 vb = lds_frag(s2, 64, tok3, kc * 2 + 1);
            float p = 0.f;
            #pragma unroll
            for (int j = 0; j < 8; ++j) p = fmaf(bf2f((u16)va[j]), w3[j], p);
            #pragma unroll
            for (int j = 0; j < 8; ++j) p = fmaf(bf2f((u16)vb[j]), w3[8 + j], p);
            p += __shfl_xor(p, 1);
            p += __shfl_xor(p, 2);
            if (kc == 0) {
                const float val = p + biasp[OB_S3 + e];
                if (e < 5)
                    __builtin_nontemporal_store(
                        val, out + OFF_SCOREALL + (size_t)e * N_TOK + row0 + tok3);
                fscore = fmaf(wgs, val, fscore);
            }
        }
    }

    if (kc == 0)
        out[OFF_SCORE + row0 + tok3] = fscore;
}

// ---------------------------------------------------------------------------
__global__ __launch_bounds__(256)
void convert_x(const float* __restrict__ x, u16* __restrict__ xb)
{
    const size_t i = ((size_t)blockIdx.x * 256 + threadIdx.x) * 4;
    float4 v = *(const float4*)(x + i);
    ushort4 o;
    o.x = f2bf(v.x); o.y = f2bf(v.y); o.z = f2bf(v.z); o.w = f2bf(v.w);
    *(ushort4*)(xb + i) = o;
}

// Weight convert+transpose: src fp32 [nz][K][H] -> dst bf16 [nz][H][K]
struct WDesc { const float* src; u32 dstOff; int K, H, nz; };
struct WTable { WDesc d[10]; };

__global__ __launch_bounds__(256)
void convert_w(WTable t, u16* __restrict__ dst)
{
    const WDesc dd = t.d[blockIdx.y];
    const int total = dd.K * dd.H * dd.nz;
    const int idx = blockIdx.x * 256 + threadIdx.x;
    if (idx < total) {
        const int kh = dd.K * dd.H;
        const int e = idx / kh;
        const int r = idx - e * kh;
        const int h = r / dd.K;
        const int k = r - h * dd.K;
        const float v = dd.src[(size_t)e * kh + (size_t)k * dd.H + h];
        dst[dd.dstOff + idx] = f2bf(v);
    }
}

// Flat fp32 gather-pack (biases + score L3 weights)
struct CDesc { const float* src; u32 dstOff; u32 n; };
struct CTable { CDesc d[14]; };

__global__ __launch_bounds__(256)
void pack_f32(CTable t, float* __restrict__ dst)
{
    const CDesc dd = t.d[blockIdx.y];
    const u32 i = blockIdx.x * 256 + threadIdx.x;
    if (i < dd.n) dst[dd.dstOff + i] = dd.src[i];
}

// ---------------------------------------------------------------------------
extern "C" void kernel_launch(void* const* d_in, const int* in_sizes, int n_in,
                              void* d_out, int out_size, void* d_ws, size_t ws_size,
                              hipStream_t stream)
{
    (void)in_sizes; (void)n_in; (void)out_size; (void)ws_size;

    const float* x   = (const float*)d_in[0];
    const float* rw1 = (const float*)d_in[1];
    const float* rb1 = (const float*)d_in[2];
    const float* rw2 = (const float*)d_in[3];
    const float* rb2 = (const float*)d_in[4];
    const float* rw3 = (const float*)d_in[5];
    const float* rb3 = (const float*)d_in[6];

    float* out = (float*)d_out;
    char* ws = (char*)d_ws;

    // ---- workspace layout ----
    u16*   xb    = (u16*)(ws);                  // [N,128] bf16        12,582,912 B
    u16*   wtb   = (u16*)(ws + 12582912);       // packed bf16 W        1,843,200 B
    float* biasp = (float*)(ws + 14426368);     // packed fp32             21,336 B
    float* part  = (float*)(ws + 14447744);     // [192,5]
    float* wtok  = (float*)(ws + 14451712);     // [5][N] gate weights    983,040 B
    float* rh1   = (float*)(ws + 15434752);     // [N,256] fp32        50,331,648 B
    float* rh2   = (float*)(ws + 65766400);     // [N,128] fp32        25,165,824 B

    const dim3 blk(256);

    // ---- router (fp32: topk_idx must match reference ordering exactly) ----
    mlp_gemm<true ><<<dim3(N_TOK / 128, 2), blk, 0, stream>>>(x,   rw1, rb1, rh1, 128, 256);
    mlp_gemm<true ><<<dim3(N_TOK / 128, 1), blk, 0, stream>>>(rh1, rw2, rb2, rh2, 256, 128);
    router_l3post<<<dim3(N_TOK / 256), blk, 0, stream>>>(
        rh2, rw3, rb3, out + OFF_LOGITS, out + OFF_IDX, wtok, part);
    aux_kernel<<<dim3(1), blk, 0, stream>>>(part, out + OFF_AUX);

    // ---- conversions / packing ----
    convert_x<<<dim3(N_TOK * 128 / 1024), blk, 0, stream>>>(x, xb);
    {
        WTable t;
        t.d[0] = { (const float*)d_in[19], O_T1,              128, 256, 5 };
        t.d[1] = { (const float*)d_in[7],  O_T1 + 5 * 32768,  128, 256, 1 };
        t.d[2] = { (const float*)d_in[21], O_T2,              256, 256, 5 };
        t.d[3] = { (const float*)d_in[9],  O_T2 + 5 * 65536,  256, 256, 1 };
        t.d[4] = { (const float*)d_in[23], O_T3,              256, 120, 5 };
        t.d[5] = { (const float*)d_in[11], O_T3 + 5 * 30720,  256, 120, 1 };
        t.d[6] = { (const float*)d_in[25], O_S1,              128, 128, 5 };
        t.d[7] = { (const float*)d_in[13], O_S1 + 5 * 16384,  128, 128, 1 };
        t.d[8] = { (const float*)d_in[27], O_S2,              128,  64, 5 };
        t.d[9] = { (const float*)d_in[15], O_S2 + 5 * 8192,   128,  64, 1 };
        convert_w<<<dim3(1280, 10), blk, 0, stream>>>(t, wtb);
    }
    {
        CTable t;
        t.d[0]  = { (const float*)d_in[20], OB_T1,        1280 };
        t.d[1]  = { (const float*)d_in[8],  OB_T1 + 1280,  256 };
        t.d[2]  = { (const float*)d_in[22], OB_T2,        1280 };
        t.d[3]  = { (const float*)d_in[10], OB_T2 + 1280,  256 };
        t.d[4]  = { (const float*)d_in[24], OB_T3,         600 };
        t.d[5]  = { (const float*)d_in[12], OB_T3 + 600,   120 };
        t.d[6]  = { (const float*)d_in[26], OB_S1,         640 };
        t.d[7]  = { (const float*)d_in[14], OB_S1 + 640,   128 };
        t.d[8]  = { (const float*)d_in[28], OB_S2,         320 };
        t.d[9]  = { (const float*)d_in[16], OB_S2 + 320,    64 };
        t.d[10] = { (const float*)d_in[29], OW_S3,         320 };
        t.d[11] = { (const float*)d_in[17], OW_S3 + 320,    64 };
        t.d[12] = { (const float*)d_in[30], OB_S3,           5 };
        t.d[13] = { (const float*)d_in[18], OB_S3 + 5,       1 };
        pack_f32<<<dim3(5, 14), blk, 0, stream>>>(t, biasp);
    }

    // ---- fused expert paths ----
    expert_traj <<<dim3(N_TOK / 64), dim3(512), 0, stream>>>(xb, wtb, biasp, wtok, out);
    expert_score<<<dim3(N_TOK / 64), dim3(256), 0, stream>>>(xb, wtb, biasp, wtok, out);
}

// Round 7
// 517.543 us; speedup vs baseline: 1.6552x; 1.0500x over previous
//
#include <hip/hip_runtime.h>
#include <hip/hip_bf16.h>
#include <cstdint>
#include <cstddef>

// Problem constants
static constexpr int N_TOK = 49152;     // B*M = 8192*6
// d_out offsets (floats), outputs concatenated in reference return order
static constexpr size_t OFF_TRAJ     = 0;          // [N,120]
static constexpr size_t OFF_SCORE    = 5898240;    // [N]
static constexpr size_t OFF_LOGITS   = 5947392;    // [N,5]
static constexpr size_t OFF_IDX      = 6193152;    // [N,2]  (ints stored as floats)
static constexpr size_t OFF_AUX      = 6291456;    // [1]
static constexpr size_t OFF_TRAJALL  = 6291457;    // [5,N,120]
static constexpr size_t OFF_SCOREALL = 35782657;   // [5,N]

typedef short s16x8 __attribute__((ext_vector_type(8)));
typedef float f32x4 __attribute__((ext_vector_type(4)));
typedef f32x4 f32x4u __attribute__((aligned(4)));   // reduced-alignment variant
typedef unsigned int u32;
typedef unsigned short u16;

// packed bf16 weight offsets (u16 elems): [6][H][K] per layer (experts 0-4, shared=5)
static constexpr u32 O_T1 = 0,      O_T2 = 196608, O_T3 = 589824;
static constexpr u32 O_S1 = 774144, O_S2 = 872448;
// packed fp32 offsets (floats)
static constexpr u32 OB_T1 = 0, OB_T2 = 1536, OB_T3 = 3072, OB_S1 = 3792, OB_S2 = 4560;
static constexpr u32 OW_S3 = 4944, OB_S3 = 5328;

__device__ __forceinline__ float gelu_f(float x) {
    return 0.5f * x * (1.0f + erff(x * 0.70710678118654752440f));
}
__device__ __forceinline__ float bf2f(u16 u) {
    return __uint_as_float(((u32)u) << 16);
}
__device__ __forceinline__ u16 f2bf(float v) {
    return ((__hip_bfloat16_raw)__float2bfloat16(v)).x;
}
__device__ __forceinline__ void gload16(const u16* g, u16* l) {
    __builtin_amdgcn_global_load_lds(
        (const __attribute__((address_space(1))) u32*)g,
        (__attribute__((address_space(3))) u32*)l, 16, 0, 0);
}
#define MFMA16(a, b, c) __builtin_amdgcn_mfma_f32_16x16x32_bf16(a, b, c, 0, 0, 0)

// swizzled LDS fragment read: logical (row r, 16B-chunk c) at chunk slot c^(r&7)
__device__ __forceinline__ s16x8 lds_frag(const u16* buf, int RBu16, int r, int c) {
    return *(const s16x8*)&buf[r * RBu16 + ((c ^ (r & 7)) << 3)];
}
// swizzled 8B LDS store of 4 consecutive bf16 cols (colb % 4 == 0)
__device__ __forceinline__ void lds_store4(u16* buf, int RBu16, int r, int colb,
                                           float v0, float v1, float v2, float v3) {
    const int ch = (colb >> 3) ^ (r & 7);
    ushort4 st = { f2bf(v0), f2bf(v1), f2bf(v2), f2bf(v3) };
    *(ushort4*)&buf[r * RBu16 + ch * 8 + (colb & 7)] = st;
}
__device__ __forceinline__ void nt_store4u(float* p, f32x4 v) {
    __builtin_nontemporal_store(v, (f32x4u*)p);     // 4B-aligned path
}

// ---------------------------------------------------------------------------
// fp32 tile GEMM (router L1/L2 only; topk_idx needs fp32-exact logits).
// ---------------------------------------------------------------------------
template<bool GELU>
__global__ __launch_bounds__(256)
void mlp_gemm(const float* __restrict__ A, const float* __restrict__ W,
              const float* __restrict__ bias, float* __restrict__ C,
              int Kd, int H)
{
    __shared__ float As[16][128];
    __shared__ float Ws[16][132];

    const int tid  = threadIdx.x;
    const int tx   = tid & 15;
    const int ty   = tid >> 4;
    const int row0 = blockIdx.x * 128;
    const int col0 = blockIdx.y * 128;
    const int lm = tid >> 1;
    const int lk = (tid & 1) * 8;

    float acc[8][8] = {};

    for (int k0 = 0; k0 < Kd; k0 += 16) {
        const float* src = A + (size_t)(row0 + lm) * Kd + k0 + lk;
        float4 f0 = *(const float4*)src;
        float4 f1 = *(const float4*)(src + 4);
        As[lk + 0][lm] = f0.x; As[lk + 1][lm] = f0.y;
        As[lk + 2][lm] = f0.z; As[lk + 3][lm] = f0.w;
        As[lk + 4][lm] = f1.x; As[lk + 5][lm] = f1.y;
        As[lk + 6][lm] = f1.z; As[lk + 7][lm] = f1.w;
        {
            const float* wsrc = W + (size_t)(k0 + ty) * H + col0 + tx * 8;
            float4 g0 = *(const float4*)wsrc;
            float4 g1 = *(const float4*)(wsrc + 4);
            *(float4*)&Ws[ty][tx * 8]     = g0;
            *(float4*)&Ws[ty][tx * 8 + 4] = g1;
        }
        __syncthreads();
        #pragma unroll
        for (int kk = 0; kk < 16; ++kk) {
            float a[8], w[8];
            *(float4*)&a[0] = *(const float4*)&As[kk][ty * 8];
            *(float4*)&a[4] = *(const float4*)&As[kk][ty * 8 + 4];
            *(float4*)&w[0] = *(const float4*)&Ws[kk][tx * 8];
            *(float4*)&w[4] = *(const float4*)&Ws[kk][tx * 8 + 4];
            #pragma unroll
            for (int i = 0; i < 8; ++i)
                #pragma unroll
                for (int j = 0; j < 8; ++j)
                    acc[i][j] = fmaf(a[i], w[j], acc[i][j]);
        }
        __syncthreads();
    }

    #pragma unroll
    for (int i = 0; i < 8; ++i) {
        const int r = row0 + ty * 8 + i;
        #pragma unroll
        for (int j = 0; j < 8; ++j) {
            const int c = col0 + tx * 8 + j;
            float v = acc[i][j] + bias[c];
            if (GELU) v = gelu_f(v);
            C[(size_t)r * H + c] = v;
        }
    }
}

// ---------------------------------------------------------------------------
// Router L3 + softmax partials + top-2 + gates (fused).
// ---------------------------------------------------------------------------
__global__ __launch_bounds__(256)
void router_l3post(const float* __restrict__ rh2, const float* __restrict__ w3,
                   const float* __restrict__ b3, float* __restrict__ logits,
                   float* __restrict__ oidx, float* __restrict__ tp,
                   int* __restrict__ ti, float* __restrict__ wtok,
                   float* __restrict__ part)
{
    __shared__ float w3s[640];
    __shared__ float red[256];
    const int tid = threadIdx.x;
    for (int i = tid; i < 640; i += 256) w3s[i] = w3[i];
    __syncthreads();

    const int n = blockIdx.x * 256 + tid;
    const float* h = rh2 + (size_t)n * 128;

    float l[5];
    #pragma unroll
    for (int e = 0; e < 5; ++e) l[e] = b3[e];
    for (int k = 0; k < 128; k += 4) {
        float4 hv = *(const float4*)(h + k);
        #pragma unroll
        for (int e = 0; e < 5; ++e) {
            l[e] = fmaf(hv.x, w3s[(k + 0) * 5 + e], l[e]);
            l[e] = fmaf(hv.y, w3s[(k + 1) * 5 + e], l[e]);
            l[e] = fmaf(hv.z, w3s[(k + 2) * 5 + e], l[e]);
            l[e] = fmaf(hv.w, w3s[(k + 3) * 5 + e], l[e]);
        }
    }
    #pragma unroll
    for (int e = 0; e < 5; ++e) logits[(size_t)n * 5 + e] = l[e];

    // full softmax (aux loss partials)
    float m = l[0];
    #pragma unroll
    for (int e = 1; e < 5; ++e) m = fmaxf(m, l[e]);
    float p[5], s = 0.f;
    #pragma unroll
    for (int e = 0; e < 5; ++e) { p[e] = expf(l[e] - m); s += p[e]; }
    const float inv = 1.0f / s;

    #pragma unroll
    for (int e = 0; e < 5; ++e) {
        red[tid] = p[e] * inv;
        __syncthreads();
        for (int off = 128; off > 0; off >>= 1) {
            if (tid < off) red[tid] += red[tid + off];
            __syncthreads();
        }
        if (tid == 0) part[blockIdx.x * 5 + e] = red[0];
        __syncthreads();
    }

    // top-2 (ties keep lower index, matching jax.lax.top_k)
    int i0 = 0; float v0 = l[0];
    #pragma unroll
    for (int e = 1; e < 5; ++e) if (l[e] > v0) { v0 = l[e]; i0 = e; }
    int i1 = -1; float v1 = -1e30f;
    #pragma unroll
    for (int e = 0; e < 5; ++e) if (e != i0 && l[e] > v1) { v1 = l[e]; i1 = e; }

    const float t  = expf(v1 - v0);
    const float q0 = 1.0f / (1.0f + t);
    const float q1 = t / (1.0f + t);

    oidx[(size_t)n * 2]     = (float)i0;
    oidx[(size_t)n * 2 + 1] = (float)i1;
    tp[n * 2] = q0; tp[n * 2 + 1] = q1;
    ti[n * 2] = i0; ti[n * 2 + 1] = i1;
    #pragma unroll
    for (int e = 0; e < 5; ++e)
        wtok[(size_t)e * N_TOK + n] = 0.7f * (e == i0 ? q0 : (e == i1 ? q1 : 0.0f));
}

__global__ __launch_bounds__(256)
void aux_kernel(const float* __restrict__ part, float* __restrict__ aux)
{
    __shared__ float avg[5];
    const int tid = threadIdx.x;
    if (tid < 5) {
        float s = 0.f;
        for (int b = 0; b < 192; ++b) s += part[b * 5 + tid];
        avg[tid] = s / (float)N_TOK;
    }
    __syncthreads();
    if (tid == 0) {
        float ent = 0.f, l2 = 0.f;
        #pragma unroll
        for (int e = 0; e < 5; ++e) {
            ent -= avg[e] * logf(avg[e] + 1e-8f);
            float d = avg[e] - 0.2f;
            l2 += d * d;
        }
        l2 *= (1.0f / 5.0f);
        aux[0] = -ent * 0.01f + 0.01f * l2;
    }
}

// ---------------------------------------------------------------------------
// Fused trajectory path: x -> h1 -> h2 -> traj for 6 experts, 64-token blocks,
// 8 waves. After L3, the f32 output tile (64x120 = 7680 floats) is staged into
// LDS (reusing h1) and cooperatively copied to global as a CONTIGUOUS block:
// fully coalesced full-line writes.
// ---------------------------------------------------------------------------
__global__ __launch_bounds__(512, 4)
void expert_traj(const u16* __restrict__ xb, const u16* __restrict__ wtb,
                 const float* __restrict__ biasp, float* __restrict__ out,
                 float* __restrict__ shtraj)
{
    __shared__ u16 xs[64 * 128];   // 16 KB
    __shared__ u16 h1[64 * 256];   // 32 KB; reused as f32 staging [64][124]
    __shared__ u16 h2[64 * 256];   // 32 KB
    float* h1f = (float*)h1;

    const int tid  = threadIdx.x;
    const int lane = tid & 63;
    const int wave = tid >> 6;          // 0..7
    const int row0 = blockIdx.x * 64;
    const int frow = lane & 15;
    const int kgrp = lane >> 4;         // 0..3
    const int c0   = wave * 32;         // L1/L2 col slice

    // stage x tile (linear LDS dest, inverse-swizzled global source)
    #pragma unroll
    for (int i = 0; i < 2; ++i) {
        const int idx = i * 512 + tid;
        const int r = idx >> 4, c = idx & 15;
        gload16(xb + (size_t)(row0 + r) * 128 + ((c ^ (r & 7)) << 3), &xs[idx * 8]);
    }

    const int col3 = wave * 16 + kgrp * 4;                       // L3 output colbase
    const int r3   = (wave * 16 + frow) < 120 ? (wave * 16 + frow) : 119;

    // prefetch expert-0 L1 weight fragments
    s16x8 wf1[4][2];
    {
        const u16* w1p = wtb + O_T1;
        #pragma unroll
        for (int n = 0; n < 2; ++n) {
            const u16* p = w1p + (size_t)(c0 + n * 16 + frow) * 128 + kgrp * 8;
            #pragma unroll
            for (int ks = 0; ks < 4; ++ks) wf1[ks][n] = *(const s16x8*)(p + ks * 32);
        }
    }

    __syncthreads();   // xs ready (drains vmcnt)

    #pragma unroll 1
    for (int e = 0; e < 6; ++e) {
        // ---------- L1: xs[64,128] -> h1[64,256] ----------
        f32x4 acc1[4][2] = {};
        #pragma unroll
        for (int ks = 0; ks < 4; ++ks)
            #pragma unroll
            for (int m = 0; m < 4; ++m) {
                const s16x8 a = lds_frag(xs, 128, m * 16 + frow, ks * 4 + kgrp);
                #pragma unroll
                for (int n = 0; n < 2; ++n)
                    acc1[m][n] = MFMA16(wf1[ks][n], a, acc1[m][n]);
            }

        // prefetch L2 first-half weights (hidden under stores+barrier)
        const u16* w2p = wtb + O_T2 + e * 65536;
        s16x8 wf2a[4][2];
        #pragma unroll
        for (int n = 0; n < 2; ++n) {
            const u16* p = w2p + (size_t)(c0 + n * 16 + frow) * 256 + kgrp * 8;
            #pragma unroll
            for (int ks = 0; ks < 4; ++ks) wf2a[ks][n] = *(const s16x8*)(p + ks * 32);
        }

        {   // store h1 (+bias+gelu)
            const float* b1 = biasp + OB_T1 + e * 256;
            #pragma unroll
            for (int n = 0; n < 2; ++n) {
                const int colb = c0 + n * 16 + kgrp * 4;
                const f32x4 bb = *(const f32x4*)&b1[colb];
                #pragma unroll
                for (int m = 0; m < 4; ++m)
                    lds_store4(h1, 256, m * 16 + frow, colb,
                               gelu_f(acc1[m][n][0] + bb[0]),
                               gelu_f(acc1[m][n][1] + bb[1]),
                               gelu_f(acc1[m][n][2] + bb[2]),
                               gelu_f(acc1[m][n][3] + bb[3]));
            }
        }
        __syncthreads();   // B1: h1 ready

        // ---------- L2: h1 -> h2, K=256 ----------
        f32x4 acc2[4][2] = {};
        #pragma unroll
        for (int ks = 0; ks < 4; ++ks)
            #pragma unroll
            for (int m = 0; m < 4; ++m) {
                const s16x8 a = lds_frag(h1, 256, m * 16 + frow, ks * 4 + kgrp);
                #pragma unroll
                for (int n = 0; n < 2; ++n)
                    acc2[m][n] = MFMA16(wf2a[ks][n], a, acc2[m][n]);
            }
        s16x8 wf2b[4][2];
        #pragma unroll
        for (int n = 0; n < 2; ++n) {
            const u16* p = w2p + (size_t)(c0 + n * 16 + frow) * 256 + 128 + kgrp * 8;
            #pragma unroll
            for (int ks = 0; ks < 4; ++ks) wf2b[ks][n] = *(const s16x8*)(p + ks * 32);
        }
        #pragma unroll
        for (int ks = 0; ks < 4; ++ks)
            #pragma unroll
            for (int m = 0; m < 4; ++m) {
                const s16x8 a = lds_frag(h1, 256, m * 16 + frow, (ks + 4) * 4 + kgrp);
                #pragma unroll
                for (int n = 0; n < 2; ++n)
                    acc2[m][n] = MFMA16(wf2b[ks][n], a, acc2[m][n]);
            }

        {   // store h2 (+bias+gelu)
            const float* b2 = biasp + OB_T2 + e * 256;
            #pragma unroll
            for (int n = 0; n < 2; ++n) {
                const int colb = c0 + n * 16 + kgrp * 4;
                const f32x4 bb = *(const f32x4*)&b2[colb];
                #pragma unroll
                for (int m = 0; m < 4; ++m)
                    lds_store4(h2, 256, m * 16 + frow, colb,
                               gelu_f(acc2[m][n][0] + bb[0]),
                               gelu_f(acc2[m][n][1] + bb[1]),
                               gelu_f(acc2[m][n][2] + bb[2]),
                               gelu_f(acc2[m][n][3] + bb[3]));
            }
        }
        __syncthreads();   // B2: h2 ready; all h1 reads done -> h1f reusable

        // prefetch L3 weights + next-expert L1 weights
        s16x8 wf3[8];
        {
            const u16* w3p = wtb + O_T3 + e * 30720 + (size_t)r3 * 256 + kgrp * 8;
            #pragma unroll
            for (int ks = 0; ks < 8; ++ks) wf3[ks] = *(const s16x8*)(w3p + ks * 32);
        }
        if (e < 5) {
            const u16* w1p = wtb + O_T1 + (e + 1) * 32768;
            #pragma unroll
            for (int n = 0; n < 2; ++n) {
                const u16* p = w1p + (size_t)(c0 + n * 16 + frow) * 128 + kgrp * 8;
                #pragma unroll
                for (int ks = 0; ks < 4; ++ks) wf1[ks][n] = *(const s16x8*)(p + ks * 32);
            }
        }

        // ---------- L3: h2 -> traj[64,120] ----------
        f32x4 acc3[4] = {};
        #pragma unroll
        for (int ks = 0; ks < 8; ++ks)
            #pragma unroll
            for (int m = 0; m < 4; ++m) {
                const s16x8 a = lds_frag(h2, 256, m * 16 + frow, ks * 4 + kgrp);
                acc3[m] = MFMA16(wf3[ks], a, acc3[m]);
            }

        // stage f32 tile into h1f[64][124] (lane: token m*16+frow, cols col3..+3)
        if (col3 < 120) {
            const f32x4 bb = *(const f32x4*)&biasp[OB_T3 + e * 120 + col3];
            #pragma unroll
            for (int m = 0; m < 4; ++m) {
                f32x4 v;
                #pragma unroll
                for (int j = 0; j < 4; ++j) v[j] = acc3[m][j] + bb[j];
                *(f32x4*)&h1f[(m * 16 + frow) * 124 + col3] = v;
            }
        }
        __syncthreads();   // B3: staging complete

        // cooperative coalesced copy: 64*120 = 7680 contiguous floats = 1920 float4
        float* dst = (e < 5) ? out + OFF_TRAJALL + ((size_t)e * N_TOK + row0) * 120
                             : shtraj + (size_t)row0 * 120;
        #pragma unroll
        for (int i = 0; i < 4; ++i) {
            const int idx = i * 512 + tid;          // float4 index
            if (idx < 1920) {
                const int tok = idx / 30;
                const int colq = (idx - tok * 30) * 4;
                const f32x4 v = *(const f32x4*)&h1f[tok * 124 + colq];
                nt_store4u(dst + (size_t)idx * 4, v);
            }
        }
        __syncthreads();   // B4: copy done; h1 free for next expert
    }
}

// ---------------------------------------------------------------------------
// Final traj combine: final = 0.3*shared + 0.7*(p0*traj[i0] + p1*traj[i1])
// One float4 per thread; reads per-row contiguous -> coalesced.
// ---------------------------------------------------------------------------
__global__ __launch_bounds__(256)
void combine_traj(const float* __restrict__ trajall, const float* __restrict__ shtraj,
                  const float* __restrict__ tp, const int* __restrict__ ti,
                  float* __restrict__ ftraj)
{
    const int i4 = blockIdx.x * 256 + threadIdx.x;   // < N*30
    const int n  = i4 / 30;
    const int q4 = (i4 - n * 30) * 4;
    const int i0 = ti[n * 2], i1 = ti[n * 2 + 1];
    const float p0 = tp[n * 2], p1 = tp[n * 2 + 1];

    const f32x4 a = *(const f32x4u*)&trajall[((size_t)i0 * N_TOK + n) * 120 + q4];
    const f32x4 b = *(const f32x4u*)&trajall[((size_t)i1 * N_TOK + n) * 120 + q4];
    const f32x4 s = *(const f32x4*)&shtraj[(size_t)n * 120 + q4];
    f32x4 r;
    #pragma unroll
    for (int j = 0; j < 4; ++j)
        r[j] = 0.3f * s[j] + 0.7f * (p0 * a[j] + p1 * b[j]);
    *(f32x4*)&ftraj[(size_t)n * 120 + q4] = r;
}

// ---------------------------------------------------------------------------
// Fused score path: x -> s1 -> s2 -> score for 6 experts + combined score.
// ---------------------------------------------------------------------------
__global__ __launch_bounds__(256, 4)
void expert_score(const u16* __restrict__ xb, const u16* __restrict__ wtb,
                  const float* __restrict__ biasp, const float* __restrict__ wtok,
                  float* __restrict__ out)
{
    __shared__ u16 xs[64 * 128];   // 16 KB
    __shared__ u16 s1[64 * 128];   // 16 KB
    __shared__ u16 s2[64 * 64];    //  8 KB

    const int tid  = threadIdx.x;
    const int lane = tid & 63;
    const int wave = tid >> 6;      // 0..3
    const int row0 = blockIdx.x * 64;
    const int frow = lane & 15;
    const int kgrp = lane >> 4;
    const int c0   = wave * 32;

    #pragma unroll
    for (int i = 0; i < 4; ++i) {
        const int idx = i * 256 + tid;
        const int r = idx >> 4, c = idx & 15;
        gload16(xb + (size_t)(row0 + r) * 128 + ((c ^ (r & 7)) << 3), &xs[idx * 8]);
    }

    const int tok3 = wave * 16 + (lane >> 2);
    const int kc   = lane & 3;
    float fscore = 0.f;

    s16x8 wfa[4][2];
    {
        const u16* wp = wtb + O_S1;
        #pragma unroll
        for (int n = 0; n < 2; ++n) {
            const u16* p = wp + (size_t)(c0 + n * 16 + frow) * 128 + kgrp * 8;
            #pragma unroll
            for (int ks = 0; ks < 4; ++ks) wfa[ks][n] = *(const s16x8*)(p + ks * 32);
        }
    }

    __syncthreads();

    #pragma unroll 1
    for (int e = 0; e < 6; ++e) {
        const float wgs = (e < 5) ? wtok[(size_t)e * N_TOK + row0 + tok3] : 0.3f;

        // ---- S1: xs -> s1[64,128] ----
        f32x4 acc1[4][2] = {};
        #pragma unroll
        for (int ks = 0; ks < 4; ++ks)
            #pragma unroll
            for (int m = 0; m < 4; ++m) {
                const s16x8 a = lds_frag(xs, 128, m * 16 + frow, ks * 4 + kgrp);
                #pragma unroll
                for (int n = 0; n < 2; ++n)
                    acc1[m][n] = MFMA16(wfa[ks][n], a, acc1[m][n]);
            }
        s16x8 wfb[4];
        {
            const u16* p = wtb + O_S2 + e * 8192 + (size_t)(wave * 16 + frow) * 128 + kgrp * 8;
            #pragma unroll
            for (int ks = 0; ks < 4; ++ks) wfb[ks] = *(const s16x8*)(p + ks * 32);
        }
        {
            const float* b1 = biasp + OB_S1 + e * 128;
            #pragma unroll
            for (int n = 0; n < 2; ++n) {
                const int colb = c0 + n * 16 + kgrp * 4;
                const f32x4 bb = *(const f32x4*)&b1[colb];
                #pragma unroll
                for (int m = 0; m < 4; ++m)
                    lds_store4(s1, 128, m * 16 + frow, colb,
                               gelu_f(acc1[m][n][0] + bb[0]),
                               gelu_f(acc1[m][n][1] + bb[1]),
                               gelu_f(acc1[m][n][2] + bb[2]),
                               gelu_f(acc1[m][n][3] + bb[3]));
            }
        }
        __syncthreads();   // B1: s1 ready

        // ---- S2: s1 -> s2[64,64] ----
        f32x4 acc2[4] = {};
        #pragma unroll
        for (int ks = 0; ks < 4; ++ks)
            #pragma unroll
            for (int m = 0; m < 4; ++m) {
                const s16x8 a = lds_frag(s1, 128, m * 16 + frow, ks * 4 + kgrp);
                acc2[m] = MFMA16(wfb[ks], a, acc2[m]);
            }
        if (e < 5) {
            const u16* wp = wtb + O_S1 + (e + 1) * 16384;
            #pragma unroll
            for (int n = 0; n < 2; ++n) {
                const u16* p = wp + (size_t)(c0 + n * 16 + frow) * 128 + kgrp * 8;
                #pragma unroll
                for (int ks = 0; ks < 4; ++ks) wfa[ks][n] = *(const s16x8*)(p + ks * 32);
            }
        }
        {
            const int colb = wave * 16 + kgrp * 4;
            const float* b2 = biasp + OB_S2 + e * 64;
            const f32x4 bb = *(const f32x4*)&b2[colb];
            #pragma unroll
            for (int m = 0; m < 4; ++m)
                lds_store4(s2, 64, m * 16 + frow, colb,
                           gelu_f(acc2[m][0] + bb[0]),
                           gelu_f(acc2[m][1] + bb[1]),
                           gelu_f(acc2[m][2] + bb[2]),
                           gelu_f(acc2[m][3] + bb[3]));
        }
        __syncthreads();   // B2: s2 ready

        // ---- S3: dot64 per token ----
        {
            const float* w3 = biasp + OW_S3 + e * 64 + kc * 16;
            const s16x8 va = lds_frag(s2, 64, tok3, kc * 2);
            const s16x8 vb = lds_frag(s2, 64, tok3, kc * 2 + 1);
            float p = 0.f;
            #pragma unroll
            for (int j = 0; j < 8; ++j) p = fmaf(bf2f((u16)va[j]), w3[j], p);
            #pragma unroll
            for (int j = 0; j < 8; ++j) p = fmaf(bf2f((u16)vb[j]), w3[8 + j], p);
            p += __shfl_xor(p, 1);
            p += __shfl_xor(p, 2);
            if (kc == 0) {
                const float val = p + biasp[OB_S3 + e];
                if (e < 5)
                    out[OFF_SCOREALL + (size_t)e * N_TOK + row0 + tok3] = val;
                fscore = fmaf(wgs, val, fscore);
            }
        }
    }

    if (kc == 0)
        out[OFF_SCORE + row0 + tok3] = fscore;
}

// ---------------------------------------------------------------------------
__global__ __launch_bounds__(256)
void convert_x(const float* __restrict__ x, u16* __restrict__ xb)
{
    const size_t i = ((size_t)blockIdx.x * 256 + threadIdx.x) * 4;
    float4 v = *(const float4*)(x + i);
    ushort4 o;
    o.x = f2bf(v.x); o.y = f2bf(v.y); o.z = f2bf(v.z); o.w = f2bf(v.w);
    *(ushort4*)(xb + i) = o;
}

// Weight convert+transpose via LDS tiles (coalesced both sides):
// src fp32 [nz][K][H] -> dst bf16 [nz][H][K]
struct WDesc { const float* src; u32 dstOff; int K, H, nz; };
struct WTable { WDesc d[10]; };

__global__ __launch_bounds__(256)
void convert_w(WTable t, u16* __restrict__ dst)
{
    const WDesc dd = t.d[blockIdx.y];
    const int tilesK = dd.K >> 5;
    const int tilesH = (dd.H + 31) >> 5;
    const int tt = blockIdx.x;
    if (tt >= tilesK * tilesH * dd.nz) return;
    const int e  = tt / (tilesK * tilesH);
    const int r  = tt - e * (tilesK * tilesH);
    const int th = r / tilesK;
    const int tk = r - th * tilesK;

    __shared__ float tile[32][33];
    const int tx = threadIdx.x & 31;
    const int ty = threadIdx.x >> 5;     // 0..7

    #pragma unroll
    for (int i = 0; i < 4; ++i) {
        const int k = tk * 32 + ty + i * 8;
        const int h = th * 32 + tx;
        tile[ty + i * 8][tx] = (h < dd.H)
            ? dd.src[((size_t)e * dd.K + k) * dd.H + h] : 0.0f;
    }
    __syncthreads();
    #pragma unroll
    for (int i = 0; i < 4; ++i) {
        const int h = th * 32 + ty + i * 8;
        const int k = tk * 32 + tx;
        if (h < dd.H)
            dst[dd.dstOff + ((size_t)e * dd.H + h) * dd.K + k] = f2bf(tile[tx][ty + i * 8]);
    }
}

// Flat fp32 gather-pack (biases + score L3 weights)
struct CDesc { const float* src; u32 dstOff; u32 n; };
struct CTable { CDesc d[14]; };

__global__ __launch_bounds__(256)
void pack_f32(CTable t, float* __restrict__ dst)
{
    const CDesc dd = t.d[blockIdx.y];
    const u32 i = blockIdx.x * 256 + threadIdx.x;
    if (i < dd.n) dst[dd.dstOff + i] = dd.src[i];
}

// ---------------------------------------------------------------------------
extern "C" void kernel_launch(void* const* d_in, const int* in_sizes, int n_in,
                              void* d_out, int out_size, void* d_ws, size_t ws_size,
                              hipStream_t stream)
{
    (void)in_sizes; (void)n_in; (void)out_size; (void)ws_size;

    const float* x   = (const float*)d_in[0];
    const float* rw1 = (const float*)d_in[1];
    const float* rb1 = (const float*)d_in[2];
    const float* rw2 = (const float*)d_in[3];
    const float* rb2 = (const float*)d_in[4];
    const float* rw3 = (const float*)d_in[5];
    const float* rb3 = (const float*)d_in[6];

    float* out = (float*)d_out;
    char* ws = (char*)d_ws;

    // ---- workspace layout ----
    u16*   xb     = (u16*)(ws);                   // [N,128] bf16   12,582,912 B
    u16*   wtb    = (u16*)(ws + 12582912);        // packed bf16 W   1,843,200 B
    float* biasp  = (float*)(ws + 14426112);      // packed fp32        21,504 B
    float* part   = (float*)(ws + 14447616);      // [192,5]
    float* tp     = (float*)(ws + 14451712);      // [N,2]
    int*   ti     = (int*)  (ws + 14844928);      // [N,2]
    float* wtok   = (float*)(ws + 15238144);      // [5][N]            983,040 B
    float* shtraj = (float*)(ws + 16221184);      // [N,120] fp32   23,592,960 B
    float* rh1    = (float*)(ws + 39814144);      // [N,256] fp32   50,331,648 B
    float* rh2    = (float*)(ws + 90145792);      // [N,128] fp32   25,165,824 B

    const dim3 blk(256);

    // ---- router (fp32: topk_idx must match reference ordering exactly) ----
    mlp_gemm<true ><<<dim3(N_TOK / 128, 2), blk, 0, stream>>>(x,   rw1, rb1, rh1, 128, 256);
    mlp_gemm<true ><<<dim3(N_TOK / 128, 1), blk, 0, stream>>>(rh1, rw2, rb2, rh2, 256, 128);
    router_l3post<<<dim3(N_TOK / 256), blk, 0, stream>>>(
        rh2, rw3, rb3, out + OFF_LOGITS, out + OFF_IDX, tp, ti, wtok, part);
    aux_kernel<<<dim3(1), blk, 0, stream>>>(part, out + OFF_AUX);

    // ---- conversions / packing ----
    convert_x<<<dim3(N_TOK * 128 / 1024), blk, 0, stream>>>(x, xb);
    {
        WTable t;
        t.d[0] = { (const float*)d_in[19], O_T1,              128, 256, 5 };
        t.d[1] = { (const float*)d_in[7],  O_T1 + 5 * 32768,  128, 256, 1 };
        t.d[2] = { (const float*)d_in[21], O_T2,              256, 256, 5 };
        t.d[3] = { (const float*)d_in[9],  O_T2 + 5 * 65536,  256, 256, 1 };
        t.d[4] = { (const float*)d_in[23], O_T3,              256, 120, 5 };
        t.d[5] = { (const float*)d_in[11], O_T3 + 5 * 30720,  256, 120, 1 };
        t.d[6] = { (const float*)d_in[25], O_S1,              128, 128, 5 };
        t.d[7] = { (const float*)d_in[13], O_S1 + 5 * 16384,  128, 128, 1 };
        t.d[8] = { (const float*)d_in[27], O_S2,              128,  64, 5 };
        t.d[9] = { (const float*)d_in[15], O_S2 + 5 * 8192,   128,  64, 1 };
        convert_w<<<dim3(320, 10), blk, 0, stream>>>(t, wtb);
    }
    {
        CTable t;
        t.d[0]  = { (const float*)d_in[20], OB_T1,        1280 };
        t.d[1]  = { (const float*)d_in[8],  OB_T1 + 1280,  256 };
        t.d[2]  = { (const float*)d_in[22], OB_T2,        1280 };
        t.d[3]  = { (const float*)d_in[10], OB_T2 + 1280,  256 };
        t.d[4]  = { (const float*)d_in[24], OB_T3,         600 };
        t.d[5]  = { (const float*)d_in[12], OB_T3 + 600,   120 };
        t.d[6]  = { (const float*)d_in[26], OB_S1,         640 };
        t.d[7]  = { (const float*)d_in[14], OB_S1 + 640,   128 };
        t.d[8]  = { (const float*)d_in[28], OB_S2,         320 };
        t.d[9]  = { (const float*)d_in[16], OB_S2 + 320,    64 };
        t.d[10] = { (const float*)d_in[29], OW_S3,         320 };
        t.d[11] = { (const float*)d_in[17], OW_S3 + 320,    64 };
        t.d[12] = { (const float*)d_in[30], OB_S3,           5 };
        t.d[13] = { (const float*)d_in[18], OB_S3 + 5,       1 };
        pack_f32<<<dim3(5, 14), blk, 0, stream>>>(t, biasp);
    }

    // ---- fused expert paths ----
    expert_traj <<<dim3(N_TOK / 64), dim3(512), 0, stream>>>(xb, wtb, biasp, out, shtraj);
    expert_score<<<dim3(N_TOK / 64), dim3(256), 0, stream>>>(xb, wtb, biasp, wtok, out);

    // ---- final trajectory combine (coalesced gather) ----
    combine_traj<<<dim3(N_TOK * 30 / 256), blk, 0, stream>>>(
        out + OFF_TRAJALL, shtraj, tp, ti, out + OFF_TRAJ);
}